// Round 1
// baseline (50.342 us; speedup 1.0000x reference)
//
#include <hip/hip_runtime.h>
#include <hip/hip_bf16.h>

#define IPS 704          // INPUTS_PER_SQUARE
#define OPS 16           // OUTPUTS_PER_SQUARE
#define NSQ 64           // NUM_SQUARES
#define MAXA 32          // MAX_ACTIVE
#define BATCH_OUT 1024   // NSQ * OPS

__global__ __launch_bounds__(256) void ft_slice_kernel(
    const int* __restrict__ fidx,
    const float* __restrict__ fval,
    const float* __restrict__ weight,
    float* __restrict__ out)
{
    const int b = blockIdx.x;
    const int t = threadIdx.x;

    __shared__ int   s_idx[MAXA];
    __shared__ int   s_sq[MAXA];
    __shared__ float s_val[MAXA];

    if (t < MAXA) {
        int idx = fidx[b * MAXA + t];
        float v = fval[b * MAXA + t];
        if (idx < 0) { idx = 0; v = 0.0f; }   // empty slot -> zero contribution
        s_idx[t] = idx;
        s_sq[t]  = idx / IPS;                 // magic-mul div by const
        s_val[t] = v;
    }
    __syncthreads();

    // thread t owns output floats [t*4, t*4+4): square t>>2, cols (t&3)*4 ..
    const int my_sq  = t >> 2;
    const int my_off = (t & 3) * 4;

    float4 acc = make_float4(0.f, 0.f, 0.f, 0.f);

    #pragma unroll
    for (int m = 0; m < MAXA; ++m) {
        if (s_sq[m] == my_sq) {               // broadcast LDS read, conflict-free
            const float v = s_val[m];
            const float4 w = *reinterpret_cast<const float4*>(
                weight + (size_t)s_idx[m] * OPS + my_off);
            acc.x += v * w.x;
            acc.y += v * w.y;
            acc.z += v * w.z;
            acc.w += v * w.w;
        }
    }

    *reinterpret_cast<float4*>(out + (size_t)b * BATCH_OUT + t * 4) = acc;
}

extern "C" void kernel_launch(void* const* d_in, const int* in_sizes, int n_in,
                              void* d_out, int out_size, void* d_ws, size_t ws_size,
                              hipStream_t stream)
{
    const int*   fidx   = (const int*)d_in[0];    // (16384, 32) int32
    const float* fval   = (const float*)d_in[1];  // (16384, 32) f32
    const float* weight = (const float*)d_in[2];  // (45056, 16) f32
    float*       out    = (float*)d_out;          // (16384, 1024) f32

    const int batch = in_sizes[0] / MAXA;         // 16384

    ft_slice_kernel<<<batch, 256, 0, stream>>>(fidx, fval, weight, out);
}